// Round 3
// baseline (353.643 us; speedup 1.0000x reference)
//
#include <hip/hip_runtime.h>
#include <hip/hip_bf16.h>

typedef unsigned short u16;
typedef unsigned int   u32;
typedef __bf16 bf16_t;
typedef bf16_t bf16x8 __attribute__((ext_vector_type(8)));
typedef u16    u16x8  __attribute__((ext_vector_type(8)));
typedef float  f32x4  __attribute__((ext_vector_type(4)));

#define DIM  2048
#define SEQ  2048
#define BATCH 2
#define NH   32
#define NKVH 8
#define HD   64
#define KVDIM (NKVH*HD)   // 512
#define NQKV (DIM + 2*KVDIM)  // 3072
#define SCALE 0.125f

__device__ __forceinline__ float b2f(u16 u) {
  union { u32 i; float f; } v; v.i = ((u32)u) << 16; return v.f;
}
__device__ __forceinline__ u16 f2b(float f) {
  union { float f; u32 i; } v; v.f = f;
  u32 x = v.i;
  return (u16)((x + 0x7fffu + ((x >> 16) & 1u)) >> 16);  // RNE
}
__device__ __forceinline__ u32 pkbf2(float a, float b) {  // low=a, high=b
  __hip_bfloat162 h = __float22bfloat162_rn(float2{a, b});
  union { __hip_bfloat162 h; u32 u; } v; v.h = h; return v.u;
}
__device__ __forceinline__ int probe_bf16(const u32* probe) { return probe[0] != 0u; }
__device__ __forceinline__ float ext_ld(const void* p, long idx, int mode_bf16) {
  return mode_bf16 ? b2f(((const u16*)p)[idx]) : ((const float*)p)[idx];
}
__device__ __forceinline__ void gload_lds16(const u16* g, u16* l) {
  __builtin_amdgcn_global_load_lds((const __attribute__((address_space(1))) void*)g,
                                   (__attribute__((address_space(3))) void*)l, 16, 0, 0);
}

// ---------------- cast x (ext dtype) -> bf16, 8 elems/thread
// NOTE: must copy in BOTH modes (gemm_qkv always reads xb when use_xb).
__global__ void cast_x(const void* __restrict__ in, u16* __restrict__ out,
                       const u32* __restrict__ probe) {
  int mode = probe_bf16(probe);
  long base = ((long)blockIdx.x * 256 + threadIdx.x) * 8;
  if (mode) {
    *(uint4*)&out[base] = *(const uint4*)((const u16*)in + base);
  } else {
    float4 f0 = *(const float4*)((const float*)in + base);
    float4 f1 = *(const float4*)((const float*)in + base + 4);
    u16x8 t;
    t[0] = f2b(f0.x); t[1] = f2b(f0.y); t[2] = f2b(f0.z); t[3] = f2b(f0.w);
    t[4] = f2b(f1.x); t[5] = f2b(f1.y); t[6] = f2b(f1.z); t[7] = f2b(f1.w);
    *(u16x8*)&out[base] = t;
  }
}

// ---------------- fused Wq/Wk/Wv transpose into WqkvT[3072][2048]
__global__ void transpose_qkv(const void* __restrict__ Wq, const void* __restrict__ Wk,
                              const void* __restrict__ Wv, u16* __restrict__ out,
                              const u32* __restrict__ probe) {
  int mode = probe_bf16(probe);
  __shared__ u16 t[32][33];
  int xt = blockIdx.x;
  const void* in; int C, c0, obase;
  if (xt < 64)      { in = Wq; C = DIM;   c0 = xt * 32;        obase = 0; }
  else if (xt < 80) { in = Wk; C = KVDIM; c0 = (xt - 64) * 32; obase = DIM; }
  else              { in = Wv; C = KVDIM; c0 = (xt - 80) * 32; obase = DIM + KVDIM; }
  int r0 = blockIdx.y * 32;
  int tx = threadIdx.x, ty = threadIdx.y;   // (32,8)
#pragma unroll
  for (int i = 0; i < 32; i += 8)
    t[ty + i][tx] = mode ? ((const u16*)in)[(long)(r0 + ty + i) * C + c0 + tx]
                         : f2b(((const float*)in)[(long)(r0 + ty + i) * C + c0 + tx]);
  __syncthreads();
#pragma unroll
  for (int i = 0; i < 32; i += 8)
    out[(long)(obase + c0 + ty + i) * DIM + r0 + tx] = t[tx][ty + i];
}

// ---------------- Wo transpose
__global__ void transpose_w(const void* __restrict__ in, u16* __restrict__ out,
                            int R, int C, const u32* __restrict__ probe) {
  int mode = probe_bf16(probe);
  __shared__ u16 t[32][33];
  int c0 = blockIdx.x * 32, r0 = blockIdx.y * 32;
  int tx = threadIdx.x, ty = threadIdx.y;
#pragma unroll
  for (int i = 0; i < 32; i += 8)
    t[ty + i][tx] = mode ? ((const u16*)in)[(long)(r0 + ty + i) * C + c0 + tx]
                         : f2b(((const float*)in)[(long)(r0 + ty + i) * C + c0 + tx]);
  __syncthreads();
#pragma unroll
  for (int i = 0; i < 32; i += 8)
    out[(long)(c0 + ty + i) * R + r0 + tx] = t[tx][ty + i];
}

// ======== 128x128 GEMM (BK=32, 4 waves, 4x4 MFMA/wave), XOR-swizzled LDS ========

// fused QKV projection with FUSED RoPE epilogue (Q scaled by 1/8);
// V block written TRANSPOSED into Vt(B,KVH,64,S).
// RoPE pairing: column n pairs with n+32; thread holds acc[mi][ni][r] and
// acc[mi][ni+2][r] (same thread) for ni in {0,1}. cos[s][d]==cos[s][d+32]
// (tables are concat([freqs,freqs])) -> one c,s load per (row, ni).
__launch_bounds__(256)
__global__ void gemm_qkv(const void* __restrict__ A, const u16* __restrict__ Bt,
                         u16* __restrict__ Qb, u16* __restrict__ Kb, u16* __restrict__ Vt,
                         int a_half, const void* __restrict__ cosb,
                         const void* __restrict__ sinb, const u32* __restrict__ probe) {
  int pmode = probe_bf16(probe);
  int mode = a_half || pmode;
  __shared__ __align__(16) u16 As[128 * 32];
  __shared__ __align__(16) u16 Bs[128 * 32];
  int tid = threadIdx.x, lane = tid & 63, wv = tid >> 6;
  int l16 = lane & 15, q = lane >> 4;
  int bm0 = blockIdx.y * 128, bn0 = blockIdx.x * 128;
  int mbase = (wv & 1) * 64, nbase = (wv >> 1) * 64;
  int c0 = tid, c1 = tid + 256;
  int r0 = c0 >> 2, s0 = (c0 & 3) ^ ((r0 >> 1) & 3);
  int r1 = c1 >> 2, s1 = (c1 & 3) ^ ((r1 >> 1) & 3);
  const int K = DIM;
  long aoff0 = (long)(bm0 + r0) * K + s0 * 8;
  long aoff1 = (long)(bm0 + r1) * K + s1 * 8;
  long boff0 = (long)(bn0 + r0) * K + s0 * 8;
  long boff1 = (long)(bn0 + r1) * K + s1 * 8;
  int rsw = (q ^ ((l16 >> 1) & 3)) * 8;
  f32x4 acc[4][4] = {};
  for (int k0 = 0; k0 < K; k0 += 32) {
    __syncthreads();
    if (mode) {
      gload_lds16((const u16*)A + aoff0 + k0, &As[wv * 512]);
      gload_lds16((const u16*)A + aoff1 + k0, &As[2048 + wv * 512]);
    } else {
      const float* Af = (const float*)A;
      float4 f0 = *(const float4*)(Af + aoff0 + k0);
      float4 f1 = *(const float4*)(Af + aoff0 + k0 + 4);
      u16x8 t;
      t[0] = f2b(f0.x); t[1] = f2b(f0.y); t[2] = f2b(f0.z); t[3] = f2b(f0.w);
      t[4] = f2b(f1.x); t[5] = f2b(f1.y); t[6] = f2b(f1.z); t[7] = f2b(f1.w);
      *(u16x8*)&As[c0 * 8] = t;
      float4 g0 = *(const float4*)(Af + aoff1 + k0);
      float4 g1 = *(const float4*)(Af + aoff1 + k0 + 4);
      u16x8 u;
      u[0] = f2b(g0.x); u[1] = f2b(g0.y); u[2] = f2b(g0.z); u[3] = f2b(g0.w);
      u[4] = f2b(g1.x); u[5] = f2b(g1.y); u[6] = f2b(g1.z); u[7] = f2b(g1.w);
      *(u16x8*)&As[c1 * 8] = u;
    }
    gload_lds16(Bt + boff0 + k0, &Bs[wv * 512]);
    gload_lds16(Bt + boff1 + k0, &Bs[2048 + wv * 512]);
    __syncthreads();
    bf16x8 af[4], bfr[4];
#pragma unroll
    for (int mi = 0; mi < 4; mi++)
      af[mi] = *(const bf16x8*)&As[(mbase + mi * 16 + l16) * 32 + rsw];
#pragma unroll
    for (int ni = 0; ni < 4; ni++)
      bfr[ni] = *(const bf16x8*)&Bs[(nbase + ni * 16 + l16) * 32 + rsw];
#pragma unroll
    for (int mi = 0; mi < 4; mi++)
#pragma unroll
      for (int ni = 0; ni < 4; ni++)
        acc[mi][ni] = __builtin_amdgcn_mfma_f32_16x16x32_bf16(
            af[mi], bfr[ni], acc[mi][ni], 0, 0, 0);
  }
  if (bn0 < DIM + KVDIM) {   // Q or K block: fused RoPE
    u16* Cb; int ldc, ncol0; float osc;
    if (bn0 < DIM) { Cb = Qb; ldc = DIM; ncol0 = bn0; osc = SCALE; }
    else           { Cb = Kb; ldc = KVDIM; ncol0 = bn0 - DIM; osc = 1.0f; }
#pragma unroll
    for (int mi = 0; mi < 4; mi++)
#pragma unroll
      for (int r = 0; r < 4; r++) {
        int m = bm0 + mbase + mi * 16 + q * 4 + r;
        int st = m & (SEQ - 1);
#pragma unroll
        for (int ni = 0; ni < 2; ni++) {
          int d = ni * 16 + l16;
          float c  = ext_ld(cosb, (long)st * HD + d, pmode);
          float sn = ext_ld(sinb, (long)st * HD + d, pmode);
          float a = acc[mi][ni][r], b = acc[mi][ni + 2][r];
          long base = (long)m * ldc + ncol0 + nbase + d;
          Cb[base]      = f2b((a * c - b * sn) * osc);
          Cb[base + 32] = f2b((b * c + a * sn) * osc);
        }
      }
  } else {                   // V block: transposed into Vt(B,KVH,64,S)
    int vcol0 = bn0 - DIM - KVDIM;
#pragma unroll
    for (int mi = 0; mi < 4; mi++)
#pragma unroll
      for (int ni = 0; ni < 4; ni++) {
        int vcol = vcol0 + nbase + ni * 16 + l16;
        int kvh2 = vcol >> 6, d = vcol & 63;
        int m = bm0 + mbase + mi * 16 + q * 4;
        int bb = m >> 11, s = m & (SEQ - 1);
        uint2 w;
        w.x = pkbf2(acc[mi][ni][0], acc[mi][ni][1]);
        w.y = pkbf2(acc[mi][ni][2], acc[mi][ni][3]);
        *(uint2*)&Vt[((long)(bb * NKVH + kvh2) * HD + d) * SEQ + s] = w;
      }
  }
}

// output projection: AO[M,2048] bf16 * WoT[2048,2048]^T -> C (ext dtype)
__launch_bounds__(256)
__global__ void gemm_ao(const u16* __restrict__ A, const u16* __restrict__ Bt,
                        void* __restrict__ C, const u32* __restrict__ probe) {
  int mode = probe_bf16(probe);
  __shared__ __align__(16) u16 As[128 * 32];
  __shared__ __align__(16) u16 Bs[128 * 32];
  int tid = threadIdx.x, lane = tid & 63, wv = tid >> 6;
  int l16 = lane & 15, q = lane >> 4;
  int bm0 = blockIdx.y * 128, bn0 = blockIdx.x * 128;
  int mbase = (wv & 1) * 64, nbase = (wv >> 1) * 64;
  int c0 = tid, c1 = tid + 256;
  int r0 = c0 >> 2, s0 = (c0 & 3) ^ ((r0 >> 1) & 3);
  int r1 = c1 >> 2, s1 = (c1 & 3) ^ ((r1 >> 1) & 3);
  const int K = DIM;
  long aoff0 = (long)(bm0 + r0) * K + s0 * 8;
  long aoff1 = (long)(bm0 + r1) * K + s1 * 8;
  long boff0 = (long)(bn0 + r0) * K + s0 * 8;
  long boff1 = (long)(bn0 + r1) * K + s1 * 8;
  int rsw = (q ^ ((l16 >> 1) & 3)) * 8;
  f32x4 acc[4][4] = {};
  for (int k0 = 0; k0 < K; k0 += 32) {
    __syncthreads();
    gload_lds16(A + aoff0 + k0, &As[wv * 512]);
    gload_lds16(A + aoff1 + k0, &As[2048 + wv * 512]);
    gload_lds16(Bt + boff0 + k0, &Bs[wv * 512]);
    gload_lds16(Bt + boff1 + k0, &Bs[2048 + wv * 512]);
    __syncthreads();
    bf16x8 af[4], bfr[4];
#pragma unroll
    for (int mi = 0; mi < 4; mi++)
      af[mi] = *(const bf16x8*)&As[(mbase + mi * 16 + l16) * 32 + rsw];
#pragma unroll
    for (int ni = 0; ni < 4; ni++)
      bfr[ni] = *(const bf16x8*)&Bs[(nbase + ni * 16 + l16) * 32 + rsw];
#pragma unroll
    for (int mi = 0; mi < 4; mi++)
#pragma unroll
      for (int ni = 0; ni < 4; ni++)
        acc[mi][ni] = __builtin_amdgcn_mfma_f32_16x16x32_bf16(
            af[mi], bfr[ni], acc[mi][ni], 0, 0, 0);
  }
#pragma unroll
  for (int mi = 0; mi < 4; mi++)
#pragma unroll
    for (int ni = 0; ni < 4; ni++)
#pragma unroll
      for (int r = 0; r < 4; r++) {
        int m = bm0 + mbase + mi * 16 + q * 4 + r;
        int n = bn0 + nbase + ni * 16 + l16;
        if (mode) ((u16*)C)[(long)m * DIM + n] = f2b(acc[mi][ni][r]);
        else      ((float*)C)[(long)m * DIM + n] = acc[mi][ni][r];
      }
}

// ---------------- fused causal attention: double-buffered LDS K/V staging.
// grid (16, B*NH), diagonal pair {i, 31-i}; block owns 64 q-rows (wave = 16).
// Per kv-tile: ONE barrier; stage(kt+1)->other buffer issued BEFORE compute(kt)
// so the implicit vmcnt(0) drain at the next barrier is covered by compute.
// LDS: Ks 2x8K + Vs 2x8K + Ps 8K = 40 KB -> exactly 4 blocks/CU (160 KB).
__launch_bounds__(256, 4)
__global__ void attn_kernel(const u16* __restrict__ Q, const u16* __restrict__ K,
                            const u16* __restrict__ Vt, u16* __restrict__ AO) {
  __shared__ __align__(16) u16 Ks[2 * 64 * 64];  // [buf][kv][d] swizzled, 16 KB
  __shared__ __align__(16) u16 Vs[2 * 64 * 64];  // [buf][d][kv] swizzled, 16 KB
  __shared__ __align__(16) u16 Ps[4][16 * 64];   // per-wave P, swizzled, 8 KB
  int tid = threadIdx.x, lane = tid & 63, wv = tid >> 6;
  int l16 = lane & 15, q = lane >> 4;
  int i = blockIdx.x;
  int bh = blockIdx.y;
  int b = bh >> 5, h = bh & 31, kvh = h >> 2;
  const u16* Kp = K + (long)b * SEQ * KVDIM + kvh * HD;
  const u16* Vp = Vt + (long)(b * NKVH + kvh) * HD * SEQ;

  // staging chunks: tile = 512 x 16B; thread stages chunks cA=tid, cB=tid+256.
  int cA = tid, cB = tid + 256;
  int rA = cA >> 3, bA = (cA & 7) ^ (rA & 7);
  int rB = cB >> 3, bB = (cB & 7) ^ (rB & 7);
  const u16* kSrcA = Kp + (long)rA * KVDIM + bA * 8;
  const u16* kSrcB = Kp + (long)rB * KVDIM + bB * 8;
  const u16* vSrcA = Vp + (long)rA * SEQ + bA * 8;
  const u16* vSrcB = Vp + (long)rB * SEQ + bB * 8;
  u16* kDstA = &Ks[(wv * 64 + lane) * 8];        // + buf offset (0 or 4096)
  u16* kDstB = &Ks[(256 + wv * 64 + lane) * 8];
  u16* vDstA = &Vs[(wv * 64 + lane) * 8];
  u16* vDstB = &Vs[(256 + wv * 64 + lane) * 8];

  int e = l16 & 7;
  int off0 = (q ^ e) * 8;          // logical block hh=0 (elems 0..31)
  int off1 = ((4 + q) ^ e) * 8;    // logical block hh=1 (elems 32..63)

  bf16x8 ones;
#pragma unroll
  for (int j = 0; j < 8; j++) ones[j] = (bf16_t)1.0f;

#pragma unroll
  for (int ph = 0; ph < 2; ph++) {
    int t = ph ? (31 - i) : i;
    int qbase = t * 64 + wv * 16;
    const u16* Qp = Q + (long)(b * SEQ + qbase) * DIM + h * HD;
    bf16x8 aq0 = *(const bf16x8*)&Qp[l16 * DIM + q * 8];
    bf16x8 aq1 = *(const bf16x8*)&Qp[l16 * DIM + 32 + q * 8];
    f32x4 o_acc[4] = {};
    f32x4 l_acc = {};
    int qrow = qbase + l16;

    __syncthreads();   // all waves done reading LDS from previous phase
    // prologue: stage tile 0 -> buf 0
    gload_lds16(kSrcA, kDstA);
    gload_lds16(kSrcB, kDstB);
    gload_lds16(vSrcA, vDstA);
    gload_lds16(vSrcB, vDstB);
    int curo = 0;

    for (int kt = 0; kt <= t; kt++) {
      __syncthreads();   // drains vmcnt: buf[curo] staged; prev reads complete
      if (kt < t) {      // stage next tile into the other buffer
        long kk2 = (long)(kt + 1) * 64;
        int nxt = curo ^ 4096;
        gload_lds16(kSrcA + kk2 * KVDIM, kDstA + nxt);
        gload_lds16(kSrcB + kk2 * KVDIM, kDstB + nxt);
        gload_lds16(vSrcA + kk2, vDstA + nxt);
        gload_lds16(vSrcB + kk2, vDstB + nxt);
      }
      const u16* Ksb = &Ks[curo];
      const u16* Vsb = &Vs[curo];
      long kk = (long)kt * 64;

      // S^T = K·Q^T : sc[ni] rows = kv, cols = this wave's 16 q-rows
      f32x4 sc[4];
#pragma unroll
      for (int ni = 0; ni < 4; ni++) {
        bf16x8 bk0 = *(const bf16x8*)&Ksb[(ni * 16 + l16) * 64 + off0];
        bf16x8 bk1 = *(const bf16x8*)&Ksb[(ni * 16 + l16) * 64 + off1];
        f32x4 z = {};
        z = __builtin_amdgcn_mfma_f32_16x16x32_bf16(bk0, aq0, z, 0, 0, 0);
        z = __builtin_amdgcn_mfma_f32_16x16x32_bf16(bk1, aq1, z, 0, 0, 0);
        sc[ni] = z;
      }
      // p = exp(s) (Q pre-scaled by 1/8); mask only on diagonal tile
      if (kt == t) {
#pragma unroll
        for (int ni = 0; ni < 4; ni++)
#pragma unroll
          for (int r = 0; r < 4; r++) {
            int kv = (int)kk + ni * 16 + q * 4 + r;
            float p = __expf(sc[ni][r]);
            sc[ni][r] = (kv <= qrow) ? p : 0.f;
          }
      } else {
#pragma unroll
        for (int ni = 0; ni < 4; ni++)
#pragma unroll
          for (int r = 0; r < 4; r++) sc[ni][r] = __expf(sc[ni][r]);
      }
      // P store: lane holds 4 consecutive kv of row qrow=l16 -> swizzled 8B writes
#pragma unroll
      for (int ni = 0; ni < 4; ni++) {
        uint2 w;
        w.x = pkbf2(sc[ni][0], sc[ni][1]);
        w.y = pkbf2(sc[ni][2], sc[ni][3]);
        int pblk = (2 * ni + (q >> 1)) ^ e;
        *(uint2*)&Ps[wv][l16 * 64 + pblk * 8 + (q & 1) * 4] = w;
      }
      // A-fragment read (same-wave RAW; compiler inserts lgkmcnt wait)
      bf16x8 ap0 = *(const bf16x8*)&Ps[wv][l16 * 64 + off0];
      bf16x8 ap1 = *(const bf16x8*)&Ps[wv][l16 * 64 + off1];
      // l via MFMA: D[qrow][*] = sum_k P[qrow][k]
      l_acc = __builtin_amdgcn_mfma_f32_16x16x32_bf16(ap0, ones, l_acc, 0, 0, 0);
      l_acc = __builtin_amdgcn_mfma_f32_16x16x32_bf16(ap1, ones, l_acc, 0, 0, 0);
#pragma unroll
      for (int di = 0; di < 4; di++) {
        bf16x8 bv0 = *(const bf16x8*)&Vsb[(di * 16 + l16) * 64 + off0];
        bf16x8 bv1 = *(const bf16x8*)&Vsb[(di * 16 + l16) * 64 + off1];
        o_acc[di] = __builtin_amdgcn_mfma_f32_16x16x32_bf16(ap0, bv0, o_acc[di], 0, 0, 0);
        o_acc[di] = __builtin_amdgcn_mfma_f32_16x16x32_bf16(ap1, bv1, o_acc[di], 0, 0, 0);
      }
      curo ^= 4096;
    }
    long obase = (long)(b * SEQ + qbase + q * 4) * DIM + h * HD;
#pragma unroll
    for (int r = 0; r < 4; r++) {
      float inv = 1.0f / l_acc[r];
#pragma unroll
      for (int di = 0; di < 4; di++)
        AO[obase + (long)r * DIM + di * 16 + l16] = f2b(o_acc[di][r] * inv);
    }
  }
}

extern "C" void kernel_launch(void* const* d_in, const int* in_sizes, int n_in,
                              void* d_out, int out_size, void* d_ws, size_t ws_size,
                              hipStream_t stream) {
  const void* x    = d_in[0];
  const void* Wq   = d_in[1];
  const void* Wk   = d_in[2];
  const void* Wv   = d_in[3];
  const void* Wo   = d_in[4];
  const void* cosb = d_in[5];
  const void* sinb = d_in[6];
  const u32*  probe = (const u32*)d_in[7];

  // workspace: WqkvT 12M + WoT 8M + Qb 16M + Kb 4M + Vt 4M (=44M) + xb 16M opt
  u16* WqkvT = (u16*)d_ws;
  u16* WoT = WqkvT + (size_t)NQKV * DIM;
  u16* Qb  = WoT + (size_t)DIM * DIM;
  u16* Kb  = Qb  + (size_t)BATCH * SEQ * DIM;
  u16* Vt  = Kb  + (size_t)BATCH * SEQ * KVDIM;
  u16* xb  = Vt  + (size_t)BATCH * NKVH * HD * SEQ;
  u16* AO  = Qb;   // alias: each attn wave reads its own Q rows before writing them

  size_t need_xb = ((size_t)(xb - WqkvT) + (size_t)BATCH * SEQ * DIM) * sizeof(u16);
  int use_xb = ws_size >= need_xb;

  dim3 blk32(32, 8);
  transpose_qkv<<<dim3(96, 64), blk32, 0, stream>>>(Wq, Wk, Wv, WqkvT, probe);
  transpose_w<<<dim3(DIM / 32, DIM / 32), blk32, 0, stream>>>(Wo, WoT, DIM, DIM, probe);

  int M = BATCH * SEQ;  // 4096
  if (use_xb) {
    cast_x<<<(M * DIM) / (256 * 8), 256, 0, stream>>>(x, xb, probe);
    gemm_qkv<<<dim3(NQKV / 128, M / 128), 256, 0, stream>>>(xb, WqkvT, Qb, Kb, Vt, 1,
                                                            cosb, sinb, probe);
  } else {
    gemm_qkv<<<dim3(NQKV / 128, M / 128), 256, 0, stream>>>(x, WqkvT, Qb, Kb, Vt, 0,
                                                            cosb, sinb, probe);
  }

  attn_kernel<<<dim3(16, BATCH * NH), 256, 0, stream>>>(Qb, Kb, Vt, AO);

  gemm_ao<<<dim3(DIM / 128, M / 128), 256, 0, stream>>>(AO, WoT, d_out, probe);
}

// Round 4
// 331.127 us; speedup vs baseline: 1.0680x; 1.0680x over previous
//
#include <hip/hip_runtime.h>
#include <hip/hip_bf16.h>

typedef unsigned short u16;
typedef unsigned int   u32;
typedef __bf16 bf16_t;
typedef bf16_t bf16x8 __attribute__((ext_vector_type(8)));
typedef u16    u16x8  __attribute__((ext_vector_type(8)));
typedef float  f32x4  __attribute__((ext_vector_type(4)));

#define DIM  2048
#define SEQ  2048
#define BATCH 2
#define NH   32
#define NKVH 8
#define HD   64
#define KVDIM (NKVH*HD)   // 512
#define NQKV (DIM + 2*KVDIM)  // 3072
#define SCALE 0.125f

__device__ __forceinline__ float b2f(u16 u) {
  union { u32 i; float f; } v; v.i = ((u32)u) << 16; return v.f;
}
__device__ __forceinline__ u16 f2b(float f) {
  union { float f; u32 i; } v; v.f = f;
  u32 x = v.i;
  return (u16)((x + 0x7fffu + ((x >> 16) & 1u)) >> 16);  // RNE
}
__device__ __forceinline__ u32 pkbf2(float a, float b) {  // low=a, high=b
  __hip_bfloat162 h = __float22bfloat162_rn(float2{a, b});
  union { __hip_bfloat162 h; u32 u; } v; v.h = h; return v.u;
}
__device__ __forceinline__ int probe_bf16(const u32* probe) { return probe[0] != 0u; }
__device__ __forceinline__ float ext_ld(const void* p, long idx, int mode_bf16) {
  return mode_bf16 ? b2f(((const u16*)p)[idx]) : ((const float*)p)[idx];
}
__device__ __forceinline__ void gload_lds16(const u16* g, u16* l) {
  __builtin_amdgcn_global_load_lds((const __attribute__((address_space(1))) void*)g,
                                   (__attribute__((address_space(3))) void*)l, 16, 0, 0);
}

struct SwapT   { static constexpr bool value = true;  };
struct NoSwapT { static constexpr bool value = false; };

// ---------------- cast x (ext dtype) -> bf16, 8 elems/thread
// bf16 input: gemm_qkv reads x directly (probe-selected); early-exit here.
__global__ void cast_x(const void* __restrict__ in, u16* __restrict__ out,
                       const u32* __restrict__ probe) {
  int mode = probe_bf16(probe);
  if (mode) return;
  long base = ((long)blockIdx.x * 256 + threadIdx.x) * 8;
  float4 f0 = *(const float4*)((const float*)in + base);
  float4 f1 = *(const float4*)((const float*)in + base + 4);
  u16x8 t;
  t[0] = f2b(f0.x); t[1] = f2b(f0.y); t[2] = f2b(f0.z); t[3] = f2b(f0.w);
  t[4] = f2b(f1.x); t[5] = f2b(f1.y); t[6] = f2b(f1.z); t[7] = f2b(f1.w);
  *(u16x8*)&out[base] = t;
}

// ---------------- fused Wq/Wk/Wv transpose into WqkvT[3072][2048]
__global__ void transpose_qkv(const void* __restrict__ Wq, const void* __restrict__ Wk,
                              const void* __restrict__ Wv, u16* __restrict__ out,
                              const u32* __restrict__ probe) {
  int mode = probe_bf16(probe);
  __shared__ u16 t[32][33];
  int xt = blockIdx.x;
  const void* in; int C, c0, obase;
  if (xt < 64)      { in = Wq; C = DIM;   c0 = xt * 32;        obase = 0; }
  else if (xt < 80) { in = Wk; C = KVDIM; c0 = (xt - 64) * 32; obase = DIM; }
  else              { in = Wv; C = KVDIM; c0 = (xt - 80) * 32; obase = DIM + KVDIM; }
  int r0 = blockIdx.y * 32;
  int tx = threadIdx.x, ty = threadIdx.y;   // (32,8)
#pragma unroll
  for (int i = 0; i < 32; i += 8)
    t[ty + i][tx] = mode ? ((const u16*)in)[(long)(r0 + ty + i) * C + c0 + tx]
                         : f2b(((const float*)in)[(long)(r0 + ty + i) * C + c0 + tx]);
  __syncthreads();
#pragma unroll
  for (int i = 0; i < 32; i += 8)
    out[(long)(obase + c0 + ty + i) * DIM + r0 + tx] = t[tx][ty + i];
}

// ---------------- Wo transpose
__global__ void transpose_w(const void* __restrict__ in, u16* __restrict__ out,
                            int R, int C, const u32* __restrict__ probe) {
  int mode = probe_bf16(probe);
  __shared__ u16 t[32][33];
  int c0 = blockIdx.x * 32, r0 = blockIdx.y * 32;
  int tx = threadIdx.x, ty = threadIdx.y;
#pragma unroll
  for (int i = 0; i < 32; i += 8)
    t[ty + i][tx] = mode ? ((const u16*)in)[(long)(r0 + ty + i) * C + c0 + tx]
                         : f2b(((const float*)in)[(long)(r0 + ty + i) * C + c0 + tx]);
  __syncthreads();
#pragma unroll
  for (int i = 0; i < 32; i += 8)
    out[(long)(c0 + ty + i) * R + r0 + tx] = t[tx][ty + i];
}

// ---------------- RoPE on Q and K in one launch; Q additionally scaled by 1/8
__global__ void rope_both(u16* __restrict__ Qb, u16* __restrict__ Kb,
                          const void* __restrict__ cosb, const void* __restrict__ sinb,
                          const u32* __restrict__ probe) {
  int mode = probe_bf16(probe);
  long gid = (long)blockIdx.x * 256 + threadIdx.x;
  const long NQp = (long)BATCH * SEQ * NH * 32;   // Q pair-slots
  u16* base_p; int n_heads; long t; float osc;
  if (gid < NQp) { base_p = Qb; n_heads = NH; t = gid; osc = SCALE; }
  else           { base_p = Kb; n_heads = NKVH; t = gid - NQp; osc = 1.0f; }
  int pair = t & 31;
  long t2 = t >> 5;
  int h = (int)(t2 % n_heads);
  long row = t2 / n_heads;
  int s = (int)(row & (SEQ - 1));
  long base = row * (n_heads * HD) + h * HD + pair;
  float q0 = b2f(base_p[base]), q1 = b2f(base_p[base + 32]);
  float c0 = ext_ld(cosb, (long)s * HD + pair, mode);
  float c1 = ext_ld(cosb, (long)s * HD + pair + 32, mode);
  float s0 = ext_ld(sinb, (long)s * HD + pair, mode);
  float s1 = ext_ld(sinb, (long)s * HD + pair + 32, mode);
  base_p[base]      = f2b((q0 * c0 - q1 * s0) * osc);
  base_p[base + 32] = f2b((q1 * c1 + q0 * s1) * osc);
}

// ======== 128x128 GEMM (BK=32, 4 waves, 4x4 MFMA/wave), XOR-swizzled LDS ========
// mfma(X,Y): D reg-dim = X row index, lane-dim = Y row index (verified layout).
// Q/K blocks use SWAPPED operands (n in reg dim) -> uint2 stores (4 consec n).
// V block keeps unswapped loop (m in reg dim) -> uint2 stores along Vt's s-dim.
// XCD-aware swizzle: each XCD owns a contiguous x-chunk (B-panels fit its L2).

__launch_bounds__(256)
__global__ void gemm_qkv(const void* __restrict__ x, const u16* __restrict__ xb,
                         int use_xb, const u16* __restrict__ Bt,
                         u16* __restrict__ Qb, u16* __restrict__ Kb, u16* __restrict__ Vt,
                         const u32* __restrict__ probe) {
  int pmode = probe_bf16(probe);
  int mode = (use_xb || pmode) ? 1 : 0;
  const u16* A16 = pmode ? (const u16*)x : xb;
  const float* Af = (const float*)x;
  __shared__ __align__(16) u16 As[128 * 32];
  __shared__ __align__(16) u16 Bs[128 * 32];
  int tid = threadIdx.x, lane = tid & 63, wv = tid >> 6;
  int l16 = lane & 15, q = lane >> 4;
  // XCD swizzle: grid (24,32) -> 768 wgs, 96/XCD; x-chunk of 3 per XCD.
  int wg = blockIdx.y * 24 + blockIdx.x;
  int xcd = wg & 7, tch = wg >> 3;
  int bm0 = (tch / 3) * 128;
  int bn0 = (xcd * 3 + tch % 3) * 128;
  int mbase = (wv & 1) * 64, nbase = (wv >> 1) * 64;
  int c0 = tid, c1 = tid + 256;
  int r0 = c0 >> 2, s0 = (c0 & 3) ^ ((r0 >> 1) & 3);
  int r1 = c1 >> 2, s1 = (c1 & 3) ^ ((r1 >> 1) & 3);
  const int K = DIM;
  long aoff0 = (long)(bm0 + r0) * K + s0 * 8;
  long aoff1 = (long)(bm0 + r1) * K + s1 * 8;
  long boff0 = (long)(bn0 + r0) * K + s0 * 8;
  long boff1 = (long)(bn0 + r1) * K + s1 * 8;
  int rsw = (q ^ ((l16 >> 1) & 3)) * 8;
  f32x4 acc[4][4] = {};

  auto kloop = [&](auto tag) {
    constexpr bool SWAP = decltype(tag)::value;
    for (int k0 = 0; k0 < K; k0 += 32) {
      __syncthreads();
      if (mode) {
        gload_lds16(A16 + aoff0 + k0, &As[wv * 512]);
        gload_lds16(A16 + aoff1 + k0, &As[2048 + wv * 512]);
      } else {
        float4 f0 = *(const float4*)(Af + aoff0 + k0);
        float4 f1 = *(const float4*)(Af + aoff0 + k0 + 4);
        u16x8 t;
        t[0] = f2b(f0.x); t[1] = f2b(f0.y); t[2] = f2b(f0.z); t[3] = f2b(f0.w);
        t[4] = f2b(f1.x); t[5] = f2b(f1.y); t[6] = f2b(f1.z); t[7] = f2b(f1.w);
        *(u16x8*)&As[c0 * 8] = t;
        float4 g0 = *(const float4*)(Af + aoff1 + k0);
        float4 g1 = *(const float4*)(Af + aoff1 + k0 + 4);
        u16x8 u;
        u[0] = f2b(g0.x); u[1] = f2b(g0.y); u[2] = f2b(g0.z); u[3] = f2b(g0.w);
        u[4] = f2b(g1.x); u[5] = f2b(g1.y); u[6] = f2b(g1.z); u[7] = f2b(g1.w);
        *(u16x8*)&As[c1 * 8] = u;
      }
      gload_lds16(Bt + boff0 + k0, &Bs[wv * 512]);
      gload_lds16(Bt + boff1 + k0, &Bs[2048 + wv * 512]);
      __syncthreads();
      bf16x8 af[4], bfr[4];
#pragma unroll
      for (int mi = 0; mi < 4; mi++)
        af[mi] = *(const bf16x8*)&As[(mbase + mi * 16 + l16) * 32 + rsw];
#pragma unroll
      for (int ni = 0; ni < 4; ni++)
        bfr[ni] = *(const bf16x8*)&Bs[(nbase + ni * 16 + l16) * 32 + rsw];
#pragma unroll
      for (int mi = 0; mi < 4; mi++)
#pragma unroll
        for (int ni = 0; ni < 4; ni++) {
          if constexpr (SWAP)
            acc[mi][ni] = __builtin_amdgcn_mfma_f32_16x16x32_bf16(
                bfr[ni], af[mi], acc[mi][ni], 0, 0, 0);
          else
            acc[mi][ni] = __builtin_amdgcn_mfma_f32_16x16x32_bf16(
                af[mi], bfr[ni], acc[mi][ni], 0, 0, 0);
        }
    }
  };

  if (bn0 < DIM + KVDIM) {   // Q or K block: swapped (n in reg dim)
    kloop(SwapT{});
    u16* Cb; int ldc, ncol0;
    if (bn0 < DIM) { Cb = Qb; ldc = DIM; ncol0 = bn0; }
    else           { Cb = Kb; ldc = KVDIM; ncol0 = bn0 - DIM; }
#pragma unroll
    for (int mi = 0; mi < 4; mi++)
#pragma unroll
      for (int ni = 0; ni < 4; ni++) {
        int m = bm0 + mbase + mi * 16 + l16;
        int n0 = ncol0 + nbase + ni * 16 + q * 4;
        uint2 w;
        w.x = pkbf2(acc[mi][ni][0], acc[mi][ni][1]);
        w.y = pkbf2(acc[mi][ni][2], acc[mi][ni][3]);
        *(uint2*)&Cb[(long)m * ldc + n0] = w;
      }
  } else {                   // V block: unswapped; transposed into Vt(B,KVH,64,S)
    kloop(NoSwapT{});
    int vcol0 = bn0 - DIM - KVDIM;
#pragma unroll
    for (int mi = 0; mi < 4; mi++)
#pragma unroll
      for (int ni = 0; ni < 4; ni++) {
        int vcol = vcol0 + nbase + ni * 16 + l16;
        int kvh2 = vcol >> 6, d = vcol & 63;
        int m = bm0 + mbase + mi * 16 + q * 4;
        int bb = m >> 11, s = m & (SEQ - 1);
        uint2 w;
        w.x = pkbf2(acc[mi][ni][0], acc[mi][ni][1]);
        w.y = pkbf2(acc[mi][ni][2], acc[mi][ni][3]);
        *(uint2*)&Vt[((long)(bb * NKVH + kvh2) * HD + d) * SEQ + s] = w;
      }
  }
}

// output projection: AO[M,2048] bf16 * WoT[2048,2048]^T -> C (ext dtype)
// swapped operands everywhere -> vectorized stores (uint2 bf16 / float4 fp32).
__launch_bounds__(256)
__global__ void gemm_ao(const u16* __restrict__ A, const u16* __restrict__ Bt,
                        void* __restrict__ C, const u32* __restrict__ probe) {
  int mode = probe_bf16(probe);
  __shared__ __align__(16) u16 As[128 * 32];
  __shared__ __align__(16) u16 Bs[128 * 32];
  int tid = threadIdx.x, lane = tid & 63, wv = tid >> 6;
  int l16 = lane & 15, q = lane >> 4;
  // XCD swizzle: grid (16,32) -> 512 wgs, 64/XCD; x-chunk of 2 per XCD.
  int wg = blockIdx.y * 16 + blockIdx.x;
  int xcd = wg & 7, tch = wg >> 3;
  int bm0 = (tch / 2) * 128;
  int bn0 = (xcd * 2 + tch % 2) * 128;
  int mbase = (wv & 1) * 64, nbase = (wv >> 1) * 64;
  int c0 = tid, c1 = tid + 256;
  int r0 = c0 >> 2, s0 = (c0 & 3) ^ ((r0 >> 1) & 3);
  int r1 = c1 >> 2, s1 = (c1 & 3) ^ ((r1 >> 1) & 3);
  const int K = DIM;
  long aoff0 = (long)(bm0 + r0) * K + s0 * 8;
  long aoff1 = (long)(bm0 + r1) * K + s1 * 8;
  long boff0 = (long)(bn0 + r0) * K + s0 * 8;
  long boff1 = (long)(bn0 + r1) * K + s1 * 8;
  int rsw = (q ^ ((l16 >> 1) & 3)) * 8;
  f32x4 acc[4][4] = {};
  for (int k0 = 0; k0 < K; k0 += 32) {
    __syncthreads();
    gload_lds16(A + aoff0 + k0, &As[wv * 512]);
    gload_lds16(A + aoff1 + k0, &As[2048 + wv * 512]);
    gload_lds16(Bt + boff0 + k0, &Bs[wv * 512]);
    gload_lds16(Bt + boff1 + k0, &Bs[2048 + wv * 512]);
    __syncthreads();
    bf16x8 af[4], bfr[4];
#pragma unroll
    for (int mi = 0; mi < 4; mi++)
      af[mi] = *(const bf16x8*)&As[(mbase + mi * 16 + l16) * 32 + rsw];
#pragma unroll
    for (int ni = 0; ni < 4; ni++)
      bfr[ni] = *(const bf16x8*)&Bs[(nbase + ni * 16 + l16) * 32 + rsw];
#pragma unroll
    for (int mi = 0; mi < 4; mi++)
#pragma unroll
      for (int ni = 0; ni < 4; ni++)
        acc[mi][ni] = __builtin_amdgcn_mfma_f32_16x16x32_bf16(
            bfr[ni], af[mi], acc[mi][ni], 0, 0, 0);   // swapped: n in reg dim
  }
#pragma unroll
  for (int mi = 0; mi < 4; mi++)
#pragma unroll
    for (int ni = 0; ni < 4; ni++) {
      int m = bm0 + mbase + mi * 16 + l16;
      int n0 = bn0 + nbase + ni * 16 + q * 4;
      if (mode) {
        uint2 w;
        w.x = pkbf2(acc[mi][ni][0], acc[mi][ni][1]);
        w.y = pkbf2(acc[mi][ni][2], acc[mi][ni][3]);
        *(uint2*)&((u16*)C)[(long)m * DIM + n0] = w;
      } else {
        float4 f;
        f.x = acc[mi][ni][0]; f.y = acc[mi][ni][1];
        f.z = acc[mi][ni][2]; f.w = acc[mi][ni][3];
        *(float4*)&((float*)C)[(long)m * DIM + n0] = f;
      }
    }
}

// ---------------- fused causal attention: double-buffered LDS K/V staging.
// grid (16, B*NH), diagonal pair {i, 31-i}; block owns 64 q-rows (wave = 16).
// Per kv-tile: ONE barrier; stage(kt+1)->other buffer issued right after the
// barrier, so its vmcnt(0) drain at the NEXT barrier is covered by compute(kt).
// LDS: Ks 2x8K + Vs 2x8K + Ps 8K = 40 KB -> exactly 4 blocks/CU (160 KB).
__launch_bounds__(256, 4)
__global__ void attn_kernel(const u16* __restrict__ Q, const u16* __restrict__ K,
                            const u16* __restrict__ Vt, u16* __restrict__ AO) {
  __shared__ __align__(16) u16 Ks[2 * 64 * 64];  // [buf][kv][d] swizzled, 16 KB
  __shared__ __align__(16) u16 Vs[2 * 64 * 64];  // [buf][d][kv] swizzled, 16 KB
  __shared__ __align__(16) u16 Ps[4][16 * 64];   // per-wave P, swizzled, 8 KB
  int tid = threadIdx.x, lane = tid & 63, wv = tid >> 6;
  int l16 = lane & 15, q = lane >> 4;
  int i = blockIdx.x;
  int bh = blockIdx.y;
  int b = bh >> 5, h = bh & 31, kvh = h >> 2;
  const u16* Kp = K + (long)b * SEQ * KVDIM + kvh * HD;
  const u16* Vp = Vt + (long)(b * NKVH + kvh) * HD * SEQ;

  int cA = tid, cB = tid + 256;
  int rA = cA >> 3, bA = (cA & 7) ^ (rA & 7);
  int rB = cB >> 3, bB = (cB & 7) ^ (rB & 7);
  const u16* kSrcA = Kp + (long)rA * KVDIM + bA * 8;
  const u16* kSrcB = Kp + (long)rB * KVDIM + bB * 8;
  const u16* vSrcA = Vp + (long)rA * SEQ + bA * 8;
  const u16* vSrcB = Vp + (long)rB * SEQ + bB * 8;
  u16* kDstA = &Ks[(wv * 64 + lane) * 8];        // + buf offset (0 or 4096)
  u16* kDstB = &Ks[(256 + wv * 64 + lane) * 8];
  u16* vDstA = &Vs[(wv * 64 + lane) * 8];
  u16* vDstB = &Vs[(256 + wv * 64 + lane) * 8];

  int e = l16 & 7;
  int off0 = (q ^ e) * 8;          // logical block hh=0 (elems 0..31)
  int off1 = ((4 + q) ^ e) * 8;    // logical block hh=1 (elems 32..63)

  bf16x8 ones;
#pragma unroll
  for (int j = 0; j < 8; j++) ones[j] = (bf16_t)1.0f;

#pragma unroll
  for (int ph = 0; ph < 2; ph++) {
    int t = ph ? (31 - i) : i;
    int qbase = t * 64 + wv * 16;
    const u16* Qp = Q + (long)(b * SEQ + qbase) * DIM + h * HD;
    bf16x8 aq0 = *(const bf16x8*)&Qp[l16 * DIM + q * 8];
    bf16x8 aq1 = *(const bf16x8*)&Qp[l16 * DIM + 32 + q * 8];
    f32x4 o_acc[4] = {};
    f32x4 l_acc = {};
    int qrow = qbase + l16;

    __syncthreads();   // all waves done reading LDS from previous phase
    gload_lds16(kSrcA, kDstA);
    gload_lds16(kSrcB, kDstB);
    gload_lds16(vSrcA, vDstA);
    gload_lds16(vSrcB, vDstB);
    int curo = 0;

    for (int kt = 0; kt <= t; kt++) {
      __syncthreads();   // drains vmcnt: buf[curo] staged; prev reads complete
      if (kt < t) {      // stage next tile into the other buffer
        long kk2 = (long)(kt + 1) * 64;
        int nxt = curo ^ 4096;
        gload_lds16(kSrcA + kk2 * KVDIM, kDstA + nxt);
        gload_lds16(kSrcB + kk2 * KVDIM, kDstB + nxt);
        gload_lds16(vSrcA + kk2, vDstA + nxt);
        gload_lds16(vSrcB + kk2, vDstB + nxt);
      }
      const u16* Ksb = &Ks[curo];
      const u16* Vsb = &Vs[curo];
      long kk = (long)kt * 64;

      f32x4 sc[4];
#pragma unroll
      for (int ni = 0; ni < 4; ni++) {
        bf16x8 bk0 = *(const bf16x8*)&Ksb[(ni * 16 + l16) * 64 + off0];
        bf16x8 bk1 = *(const bf16x8*)&Ksb[(ni * 16 + l16) * 64 + off1];
        f32x4 z = {};
        z = __builtin_amdgcn_mfma_f32_16x16x32_bf16(bk0, aq0, z, 0, 0, 0);
        z = __builtin_amdgcn_mfma_f32_16x16x32_bf16(bk1, aq1, z, 0, 0, 0);
        sc[ni] = z;
      }
      if (kt == t) {
#pragma unroll
        for (int ni = 0; ni < 4; ni++)
#pragma unroll
          for (int r = 0; r < 4; r++) {
            int kv = (int)kk + ni * 16 + q * 4 + r;
            float p = __expf(sc[ni][r]);
            sc[ni][r] = (kv <= qrow) ? p : 0.f;
          }
      } else {
#pragma unroll
        for (int ni = 0; ni < 4; ni++)
#pragma unroll
          for (int r = 0; r < 4; r++) sc[ni][r] = __expf(sc[ni][r]);
      }
#pragma unroll
      for (int ni = 0; ni < 4; ni++) {
        uint2 w;
        w.x = pkbf2(sc[ni][0], sc[ni][1]);
        w.y = pkbf2(sc[ni][2], sc[ni][3]);
        int pblk = (2 * ni + (q >> 1)) ^ e;
        *(uint2*)&Ps[wv][l16 * 64 + pblk * 8 + (q & 1) * 4] = w;
      }
      bf16x8 ap0 = *(const bf16x8*)&Ps[wv][l16 * 64 + off0];
      bf16x8 ap1 = *(const bf16x8*)&Ps[wv][l16 * 64 + off1];
      l_acc = __builtin_amdgcn_mfma_f32_16x16x32_bf16(ap0, ones, l_acc, 0, 0, 0);
      l_acc = __builtin_amdgcn_mfma_f32_16x16x32_bf16(ap1, ones, l_acc, 0, 0, 0);
#pragma unroll
      for (int di = 0; di < 4; di++) {
        bf16x8 bv0 = *(const bf16x8*)&Vsb[(di * 16 + l16) * 64 + off0];
        bf16x8 bv1 = *(const bf16x8*)&Vsb[(di * 16 + l16) * 64 + off1];
        o_acc[di] = __builtin_amdgcn_mfma_f32_16x16x32_bf16(ap0, bv0, o_acc[di], 0, 0, 0);
        o_acc[di] = __builtin_amdgcn_mfma_f32_16x16x32_bf16(ap1, bv1, o_acc[di], 0, 0, 0);
      }
      curo ^= 4096;
    }
    long obase = (long)(b * SEQ + qbase + q * 4) * DIM + h * HD;
#pragma unroll
    for (int r = 0; r < 4; r++) {
      float inv = 1.0f / l_acc[r];
#pragma unroll
      for (int di = 0; di < 4; di++)
        AO[obase + (long)r * DIM + di * 16 + l16] = f2b(o_acc[di][r] * inv);
    }
  }
}

extern "C" void kernel_launch(void* const* d_in, const int* in_sizes, int n_in,
                              void* d_out, int out_size, void* d_ws, size_t ws_size,
                              hipStream_t stream) {
  const void* x    = d_in[0];
  const void* Wq   = d_in[1];
  const void* Wk   = d_in[2];
  const void* Wv   = d_in[3];
  const void* Wo   = d_in[4];
  const void* cosb = d_in[5];
  const void* sinb = d_in[6];
  const u32*  probe = (const u32*)d_in[7];

  // workspace: WqkvT 12M + WoT 8M + Qb 16M + Kb 4M + Vt 4M (=44M) + xb 16M opt
  u16* WqkvT = (u16*)d_ws;
  u16* WoT = WqkvT + (size_t)NQKV * DIM;
  u16* Qb  = WoT + (size_t)DIM * DIM;
  u16* Kb  = Qb  + (size_t)BATCH * SEQ * DIM;
  u16* Vt  = Kb  + (size_t)BATCH * SEQ * KVDIM;
  u16* xb  = Vt  + (size_t)BATCH * NKVH * HD * SEQ;
  u16* AO  = Qb;   // alias: each attn wave reads its own Q rows before writing them

  size_t need_xb = ((size_t)(xb - WqkvT) + (size_t)BATCH * SEQ * DIM) * sizeof(u16);
  int use_xb = ws_size >= need_xb;

  dim3 blk32(32, 8);
  transpose_qkv<<<dim3(96, 64), blk32, 0, stream>>>(Wq, Wk, Wv, WqkvT, probe);
  transpose_w<<<dim3(DIM / 32, DIM / 32), blk32, 0, stream>>>(Wo, WoT, DIM, DIM, probe);

  int M = BATCH * SEQ;  // 4096
  if (use_xb) {
    cast_x<<<(M * DIM) / (256 * 8), 256, 0, stream>>>(x, xb, probe);
    gemm_qkv<<<dim3(NQKV / 128, M / 128), 256, 0, stream>>>(x, xb, 1, WqkvT, Qb, Kb, Vt, probe);
  } else {
    gemm_qkv<<<dim3(NQKV / 128, M / 128), 256, 0, stream>>>(x, nullptr, 0, WqkvT, Qb, Kb, Vt, probe);
  }

  long rope_slots = (long)M * NH * 32 + (long)M * NKVH * 32;
  rope_both<<<(int)(rope_slots / 256), 256, 0, stream>>>(Qb, Kb, cosb, sinb, probe);

  attn_kernel<<<dim3(16, BATCH * NH), 256, 0, stream>>>(Qb, Kb, Vt, AO);

  gemm_ao<<<dim3(DIM / 128, M / 128), 256, 0, stream>>>(AO, WoT, d_out, probe);
}